// Round 1
// 149.349 us; speedup vs baseline: 1.0934x; 1.0934x over previous
//
#include <hip/hip_runtime.h>

typedef __attribute__((ext_vector_type(8))) short short8;
typedef __attribute__((ext_vector_type(4))) float f32x4;
typedef __attribute__((ext_vector_type(16))) float f32x16;
typedef __attribute__((ext_vector_type(4))) unsigned short u16x4;
typedef __attribute__((ext_vector_type(4))) unsigned int u32x4;

#define T_SEQ   2048
#define NHEADS  16
#define DHEAD   64
#define DMODEL  1024
#define NBATCH  2
#define MROWS   (NBATCH * T_SEQ)   /* 4096 */

__device__ __forceinline__ unsigned short f2bf(float f) {
    unsigned int u = __float_as_uint(f);
    u += 0x7fffu + ((u >> 16) & 1u);   // round-to-nearest-even
    return (unsigned short)(u >> 16);
}

__device__ __forceinline__ unsigned int cvtpk(float lo, float hi) {
    unsigned int r;
    asm("v_cvt_pk_bf16_f32 %0, %1, %2" : "=v"(r) : "v"(lo), "v"(hi));
    return r;
}

__device__ __forceinline__ void gld_lds16(const unsigned short* g, unsigned short* l) {
    __builtin_amdgcn_global_load_lds(
        (const __attribute__((address_space(1))) void*)g,
        (__attribute__((address_space(3))) void*)l, 16, 0, 0);
}

// ---------------------------------------------------------------- converts
__global__ __launch_bounds__(256) void k_convert(const float* __restrict__ in,
                                                 unsigned short* __restrict__ out,
                                                 int n8) {
    int i = blockIdx.x * blockDim.x + threadIdx.x;
    if (i >= n8) return;
    const float4* p = (const float4*)(in + (size_t)i * 8);
    float4 a = p[0], b = p[1];
    short8 r;
    r[0] = (short)f2bf(a.x); r[1] = (short)f2bf(a.y);
    r[2] = (short)f2bf(a.z); r[3] = (short)f2bf(a.w);
    r[4] = (short)f2bf(b.x); r[5] = (short)f2bf(b.y);
    r[6] = (short)f2bf(b.z); r[7] = (short)f2bf(b.w);
    *(short8*)(out + (size_t)i * 8) = r;
}

__global__ __launch_bounds__(256) void k_convert4(const float* __restrict__ w0,
                                                  const float* __restrict__ w1,
                                                  const float* __restrict__ w2,
                                                  const float* __restrict__ w3,
                                                  unsigned short* __restrict__ out,
                                                  int n8) {
    int i = blockIdx.x * blockDim.x + threadIdx.x;
    if (i >= n8) return;
    const float* src = (blockIdx.y == 0) ? w0 : (blockIdx.y == 1) ? w1
                     : (blockIdx.y == 2) ? w2 : w3;
    unsigned short* dst = out + (size_t)blockIdx.y * (size_t)(DMODEL * DMODEL);
    const float4* p = (const float4*)(src + (size_t)i * 8);
    float4 a = p[0], b = p[1];
    short8 r;
    r[0] = (short)f2bf(a.x); r[1] = (short)f2bf(a.y);
    r[2] = (short)f2bf(a.z); r[3] = (short)f2bf(a.w);
    r[4] = (short)f2bf(b.x); r[5] = (short)f2bf(b.y);
    r[6] = (short)f2bf(b.z); r[7] = (short)f2bf(b.w);
    *(short8*)(dst + (size_t)i * 8) = r;
}

// ---------------------------------------------- staged GEMM  C = A * W^T
// m97 structure: 128x128 tile, BK=32, global_load_lds width 16, 2 barriers.
// MODE 0: fp32 row-major [M,1024] to outF (O-projection).
// MODE 1: fused QKV (Wm = [3072,1024]): n<1024 -> Q [B,H,T,64]; n<2048 -> K
//         [B,H,T,64]; else V transposed [B,H,64,T].
template <int MODE>
__global__ __launch_bounds__(256) void k_gemm_st(const unsigned short* __restrict__ A,
                                                 const unsigned short* __restrict__ Wm,
                                                 float* __restrict__ outF,
                                                 unsigned short* __restrict__ outQ,
                                                 unsigned short* __restrict__ outK,
                                                 unsigned short* __restrict__ outV) {
    __shared__ __align__(16) unsigned short smA[128 * 32];
    __shared__ __align__(16) unsigned short smB[128 * 32];
    const int tid  = threadIdx.x;
    const int lane = tid & 63;
    const int w    = tid >> 6;
    const int lr   = lane & 15;
    const int lg   = lane >> 4;
    const int m0   = blockIdx.y * 128;
    const int n0   = blockIdx.x * 128;
    const int wm   = (w >> 1) * 64;
    const int wn   = (w & 1) * 64;

    const int srow = w * 32 + (lane >> 2);
    const int scol = (lane & 3) * 8;
    const unsigned short* gA0 = A  + (size_t)(m0 + srow) * DMODEL + scol;
    const unsigned short* gB0 = Wm + (size_t)(n0 + srow) * DMODEL + scol;
    unsigned short* lA0 = smA + w * 1024;   // wave-uniform LDS base
    unsigned short* lB0 = smB + w * 1024;

    f32x4 acc[4][4];
#pragma unroll
    for (int i = 0; i < 4; i++)
#pragma unroll
        for (int j = 0; j < 4; j++) acc[i][j] = (f32x4){0.f, 0.f, 0.f, 0.f};

    for (int k0 = 0; k0 < DMODEL; k0 += 32) {
        gld_lds16(gA0 + k0, lA0);
        gld_lds16(gA0 + 16 * DMODEL + k0, lA0 + 16 * 32);
        gld_lds16(gB0 + k0, lB0);
        gld_lds16(gB0 + 16 * DMODEL + k0, lB0 + 16 * 32);
        __syncthreads();
        short8 af[4], bfr[4];
#pragma unroll
        for (int i = 0; i < 4; i++)
            af[i] = *(const short8*)&smA[(wm + 16 * i + lr) * 32 + lg * 8];
#pragma unroll
        for (int j = 0; j < 4; j++)
            bfr[j] = *(const short8*)&smB[(wn + 16 * j + lr) * 32 + lg * 8];
#pragma unroll
        for (int i = 0; i < 4; i++)
#pragma unroll
            for (int j = 0; j < 4; j++)
                acc[i][j] = __builtin_amdgcn_mfma_f32_16x16x32_bf16(af[i], bfr[j], acc[i][j], 0, 0, 0);
        __syncthreads();
    }

    if (MODE == 0) {
#pragma unroll
        for (int i = 0; i < 4; i++)
#pragma unroll
            for (int j = 0; j < 4; j++) {
                int n = n0 + wn + 16 * j + lr;
#pragma unroll
                for (int r = 0; r < 4; r++) {
                    int mm = m0 + wm + 16 * i + lg * 4 + r;
                    outF[(size_t)mm * DMODEL + n] = acc[i][j][r];
                }
            }
    } else {
        const int which = n0 >> 10;          // 0=Q 1=K 2=V
        const int nb = n0 & 1023;
#pragma unroll
        for (int i = 0; i < 4; i++)
#pragma unroll
            for (int j = 0; j < 4; j++) {
                int nloc = nb + wn + 16 * j + lr;
                int h = nloc >> 6, d = nloc & 63;
                int mb = m0 + wm + 16 * i + lg * 4;
                int b = mb >> 11, t = mb & (T_SEQ - 1);
                if (which == 2) {
                    u16x4 pk;
#pragma unroll
                    for (int r = 0; r < 4; r++) pk[r] = f2bf(acc[i][j][r]);
                    *(u16x4*)(outV + (((size_t)(b * NHEADS + h)) * DHEAD + d) * T_SEQ + t) = pk;
                } else {
                    unsigned short* dst = (which == 0) ? outQ : outK;
#pragma unroll
                    for (int r = 0; r < 4; r++)
                        dst[(((size_t)(b * NHEADS + h)) * T_SEQ + t + r) * DHEAD + d] = f2bf(acc[i][j][r]);
                }
            }
    }
}

// ------------------------------------------------------------- attention
// Swapped-QK^T flash attention, 32x32 MFMA.
// Equal-work blocks: 1024 blocks x 4 waves. Each block owns the q-tile pair
// (63-pr, pr) -> always 33 KV-tiles of work. Each q-tile is processed with a
// 4-way split-KV (wave u takes tiles u, u+4, ...), merged via LDS by a
// rotating merger wave (phase 0 -> wave 0, phase 1 -> wave 1) so the merge
// overlaps the other waves' next-phase compute.
// Q,K: [B,H,T,64] bf16.  Vt: [B,H,64,T] bf16.  O: [B,T,1024] bf16.
__global__ __launch_bounds__(256) void k_attn(const unsigned short* __restrict__ Q,
                                              const unsigned short* __restrict__ K,
                                              const unsigned short* __restrict__ Vt,
                                              unsigned short* __restrict__ O) {
    __shared__ float Msm[3][64][35];       // 3 writer slots: 32 O + m + l per lane
    const int tid  = threadIdx.x;
    const int lane = tid & 63;
    const int wv   = tid >> 6;             // 0..3
    const int l31  = lane & 31;
    const int hi   = lane >> 5;
    const bool h0  = (hi == 0);

    const int flat = blockIdx.x;           // 0..1023
    const int xc   = flat & 7;             // XCD chunk for L2 locality
    const int rest = flat >> 3;            // 0..127
    const int hh   = rest >> 5;            // 0..3
    const int pr   = rest & 31;            // pair index 0..31
    const int bh   = xc * 4 + hh;

    const size_t baseQK = (size_t)bh * T_SEQ * DHEAD;
    const size_t baseV  = (size_t)bh * DHEAD * T_SEQ;
    const unsigned short* Kb = K + baseQK;
    const float SC = 0.18033688f;          // 0.125 * log2(e)

    for (int phase = 0; phase < 2; ++phase) {
        const int qt = phase ? pr : (63 - pr);   // heavy first
        const int q0 = qt * 32;
        const int ntiles = (qt >> 1) + 1;
        const int qlane = q0 + l31;

        short8 qf[4];
#pragma unroll
        for (int dt = 0; dt < 4; dt++)
            qf[dt] = *(const short8*)(Q + baseQK + (size_t)(q0 + l31) * DHEAD + dt * 16 + hi * 8);

        f32x16 oa0, oa1;
#pragma unroll
        for (int r = 0; r < 16; r++) { oa0[r] = 0.f; oa1[r] = 0.f; }
        float m = -1e30f, l = 0.f;

        for (int tix = wv; tix < ntiles; tix += 4) {
            const int k0 = tix * 64;

            short8 vf0[4], vf1[4], kf0[4], kf1[4];
#pragma unroll
            for (int kt = 0; kt < 4; kt++) {
                vf0[kt] = *(const short8*)(Vt + baseV + (size_t)l31 * T_SEQ + k0 + kt * 16 + hi * 8);
                vf1[kt] = *(const short8*)(Vt + baseV + (size_t)(32 + l31) * T_SEQ + k0 + kt * 16 + hi * 8);
                kf0[kt] = *(const short8*)(Kb + (size_t)(k0 + l31) * DHEAD + kt * 16 + hi * 8);
                kf1[kt] = *(const short8*)(Kb + (size_t)(k0 + 32 + l31) * DHEAD + kt * 16 + hi * 8);
            }

            f32x16 s0, s1;
#pragma unroll
            for (int r = 0; r < 16; r++) { s0[r] = 0.f; s1[r] = 0.f; }
#pragma unroll
            for (int dt = 0; dt < 4; dt++)
                s0 = __builtin_amdgcn_mfma_f32_32x32x16_bf16(kf0[dt], qf[dt], s0, 0, 0, 0);
#pragma unroll
            for (int dt = 0; dt < 4; dt++)
                s1 = __builtin_amdgcn_mfma_f32_32x32x16_bf16(kf1[dt], qf[dt], s1, 0, 0, 0);

#pragma unroll
            for (int r = 0; r < 16; r++) { s0[r] *= SC; s1[r] *= SC; }
            if (tix == ntiles - 1) {
                const int thr = qlane - k0;
#pragma unroll
                for (int r = 0; r < 16; r++) {
                    const int koff = (r & 3) + 8 * (r >> 2) + 4 * hi;
                    if (koff > thr)      s0[r] = -1e30f;
                    if (koff + 32 > thr) s1[r] = -1e30f;
                }
            }

            float mt = fmaxf(s0[0], s1[0]);
#pragma unroll
            for (int r = 1; r < 16; r++) mt = fmaxf(mt, fmaxf(s0[r], s1[r]));
            mt = fmaxf(mt, __shfl_xor(mt, 32));

            if (__any(mt > m + 8.0f)) {
                float mn = fmaxf(m, mt);
                float al = exp2f(m - mn);
                m = mn; l *= al;
#pragma unroll
                for (int r = 0; r < 16; r++) { oa0[r] *= al; oa1[r] *= al; }
            }

            f32x16 p0, p1;
            float sa = 0.f, sb = 0.f;
#pragma unroll
            for (int r = 0; r < 16; r++) {
                p0[r] = exp2f(s0[r] - m);
                p1[r] = exp2f(s1[r] - m);
                sa += p0[r]; sb += p1[r];
            }
            float sum = sa + sb;
            sum += __shfl_xor(sum, 32);
            l += sum;

            unsigned int ow0[8], ow1[8], sw0[8], sw1[8];
#pragma unroll
            for (int q_ = 0; q_ < 8; q_++) {
                ow0[q_] = cvtpk(p0[2 * q_], p0[2 * q_ + 1]);
                ow1[q_] = cvtpk(p1[2 * q_], p1[2 * q_ + 1]);
            }
#pragma unroll
            for (int q_ = 0; q_ < 8; q_++) {
                sw0[q_] = __shfl_xor(ow0[q_], 32);
                sw1[q_] = __shfl_xor(ow1[q_], 32);
            }

#define PV_STEP(KT, OW, SW, J) do {                                              \
        u32x4 wvv;                                                               \
        wvv[0] = h0 ? OW[J]     : SW[J + 2];                                     \
        wvv[1] = h0 ? OW[J + 1] : SW[J + 3];                                     \
        wvv[2] = h0 ? SW[J]     : OW[J + 2];                                     \
        wvv[3] = h0 ? SW[J + 1] : OW[J + 3];                                     \
        short8 pf = __builtin_bit_cast(short8, wvv);                             \
        oa0 = __builtin_amdgcn_mfma_f32_32x32x16_bf16(vf0[KT], pf, oa0, 0, 0, 0);\
        oa1 = __builtin_amdgcn_mfma_f32_32x32x16_bf16(vf1[KT], pf, oa1, 0, 0, 0);\
    } while (0)

            PV_STEP(0, ow0, sw0, 0);
            PV_STEP(1, ow0, sw0, 4);
            PV_STEP(2, ow1, sw1, 0);
            PV_STEP(3, ow1, sw1, 4);
#undef PV_STEP
        }

        // ---- 4-way merge: 3 writer waves -> LDS, merger wave combines.
        const int merger = phase;            // rotate merger: phase0->w0, phase1->w1
        if (phase == 1) __syncthreads();     // LDS slots free (phase-0 merger done)
        if (wv != merger) {
            const int slot = wv - (wv > merger ? 1 : 0);   // 0..2
#pragma unroll
            for (int r = 0; r < 16; r++) {
                Msm[slot][lane][r]      = oa0[r];
                Msm[slot][lane][16 + r] = oa1[r];
            }
            Msm[slot][lane][32] = m;
            Msm[slot][lane][33] = l;
        }
        __syncthreads();
        if (wv == merger) {
            float ms[3], ls[3];
            float mtot = m;
#pragma unroll
            for (int s = 0; s < 3; s++) {
                ms[s] = Msm[s][lane][32];
                ls[s] = Msm[s][lane][33];
                mtot = fmaxf(mtot, ms[s]);
            }
            const float fo = exp2f(m - mtot);
            float fs[3];
            float lt = l * fo;
#pragma unroll
            for (int s = 0; s < 3; s++) {
                fs[s] = exp2f(ms[s] - mtot);
                lt += ls[s] * fs[s];
            }
            const float inv = 1.0f / lt;
            const int b = bh >> 4, h = bh & 15;
            unsigned short* orow = O + ((size_t)(b * T_SEQ + qlane)) * DMODEL + h * DHEAD;
#pragma unroll
            for (int rg = 0; rg < 4; rg++) {
                u16x4 pk0, pk1;
#pragma unroll
                for (int jj = 0; jj < 4; jj++) {
                    const int idx = 4 * rg + jj;
                    float v0 = oa0[idx] * fo;
                    float v1 = oa1[idx] * fo;
#pragma unroll
                    for (int s = 0; s < 3; s++) {
                        v0 += Msm[s][lane][idx]      * fs[s];
                        v1 += Msm[s][lane][16 + idx] * fs[s];
                    }
                    pk0[jj] = f2bf(v0 * inv);
                    pk1[jj] = f2bf(v1 * inv);
                }
                *(u16x4*)(orow + 4 * hi + 8 * rg) = pk0;
                *(u16x4*)(orow + 32 + 4 * hi + 8 * rg) = pk1;
            }
        }
    }
}

// ---------------------------------------------------------------- launch
extern "C" void kernel_launch(void* const* d_in, const int* in_sizes, int n_in,
                              void* d_out, int out_size, void* d_ws, size_t ws_size,
                              hipStream_t stream) {
    const float* x  = (const float*)d_in[0];
    // d_in[1] = causal mask (tril) -- structure is hardcoded
    const float* Wq = (const float*)d_in[2];
    const float* Wk = (const float*)d_in[3];
    const float* Wv = (const float*)d_in[4];
    const float* Wo = (const float*)d_in[5];

    unsigned short* wsu = (unsigned short*)d_ws;
    const size_t WELE = (size_t)DMODEL * DMODEL;         // 1,048,576
    unsigned short* Wo_bf = wsu + 3 * WELE;
    unsigned short* x_bf  = wsu + 4 * WELE;              // [4096,1024]; reused as attn out
    unsigned short* Qp    = wsu + 8 * WELE;              // [B,H,T,64]
    unsigned short* Kp    = wsu + 12 * WELE;             // [B,H,T,64]
    unsigned short* Vp    = wsu + 16 * WELE;             // [B,H,64,T]  (transposed)
    if (ws_size < 20 * WELE * sizeof(unsigned short)) return;  // need 40 MB

    const int n8x = (MROWS * DMODEL) / 8;   // 524288
    const int n8w = (DMODEL * DMODEL) / 8;  // 131072
    k_convert<<<dim3((n8x + 255) / 256), 256, 0, stream>>>(x, x_bf, n8x);
    k_convert4<<<dim3((n8w + 255) / 256, 4), 256, 0, stream>>>(Wq, Wk, Wv, Wo, wsu, n8w);

    // fused QKV projection: N = 3072
    k_gemm_st<1><<<dim3(3 * DMODEL / 128, MROWS / 128), 256, 0, stream>>>(
        x_bf, wsu, nullptr, Qp, Kp, Vp);

    k_attn<<<dim3(1024), 256, 0, stream>>>(Qp, Kp, Vp, x_bf);

    k_gemm_st<0><<<dim3(DMODEL / 128, MROWS / 128), 256, 0, stream>>>(
        x_bf, Wo_bf, (float*)d_out, nullptr, nullptr, nullptr);
}

// Round 2
// 145.106 us; speedup vs baseline: 1.1253x; 1.0292x over previous
//
#include <hip/hip_runtime.h>

typedef __attribute__((ext_vector_type(8))) short short8;
typedef __attribute__((ext_vector_type(4))) float f32x4;
typedef __attribute__((ext_vector_type(16))) float f32x16;
typedef __attribute__((ext_vector_type(4))) unsigned short u16x4;
typedef __attribute__((ext_vector_type(4))) unsigned int u32x4;

#define T_SEQ   2048
#define NHEADS  16
#define DHEAD   64
#define DMODEL  1024
#define NBATCH  2
#define MROWS   (NBATCH * T_SEQ)   /* 4096 */

__device__ __forceinline__ unsigned short f2bf(float f) {
    unsigned int u = __float_as_uint(f);
    u += 0x7fffu + ((u >> 16) & 1u);   // round-to-nearest-even
    return (unsigned short)(u >> 16);
}

__device__ __forceinline__ unsigned int cvtpk(float lo, float hi) {
    unsigned int r;
    asm("v_cvt_pk_bf16_f32 %0, %1, %2" : "=v"(r) : "v"(lo), "v"(hi));
    return r;
}

__device__ __forceinline__ void gld_lds16(const unsigned short* g, unsigned short* l) {
    __builtin_amdgcn_global_load_lds(
        (const __attribute__((address_space(1))) void*)g,
        (__attribute__((address_space(3))) void*)l, 16, 0, 0);
}

// ---------------------------------------------------------------- converts
__global__ __launch_bounds__(256) void k_convert(const float* __restrict__ in,
                                                 unsigned short* __restrict__ out,
                                                 int n8) {
    int i = blockIdx.x * blockDim.x + threadIdx.x;
    if (i >= n8) return;
    const float4* p = (const float4*)(in + (size_t)i * 8);
    float4 a = p[0], b = p[1];
    short8 r;
    r[0] = (short)f2bf(a.x); r[1] = (short)f2bf(a.y);
    r[2] = (short)f2bf(a.z); r[3] = (short)f2bf(a.w);
    r[4] = (short)f2bf(b.x); r[5] = (short)f2bf(b.y);
    r[6] = (short)f2bf(b.z); r[7] = (short)f2bf(b.w);
    *(short8*)(out + (size_t)i * 8) = r;
}

__global__ __launch_bounds__(256) void k_convert4(const float* __restrict__ w0,
                                                  const float* __restrict__ w1,
                                                  const float* __restrict__ w2,
                                                  const float* __restrict__ w3,
                                                  unsigned short* __restrict__ out,
                                                  int n8) {
    int i = blockIdx.x * blockDim.x + threadIdx.x;
    if (i >= n8) return;
    const float* src = (blockIdx.y == 0) ? w0 : (blockIdx.y == 1) ? w1
                     : (blockIdx.y == 2) ? w2 : w3;
    unsigned short* dst = out + (size_t)blockIdx.y * (size_t)(DMODEL * DMODEL);
    const float4* p = (const float4*)(src + (size_t)i * 8);
    float4 a = p[0], b = p[1];
    short8 r;
    r[0] = (short)f2bf(a.x); r[1] = (short)f2bf(a.y);
    r[2] = (short)f2bf(a.z); r[3] = (short)f2bf(a.w);
    r[4] = (short)f2bf(b.x); r[5] = (short)f2bf(b.y);
    r[6] = (short)f2bf(b.z); r[7] = (short)f2bf(b.w);
    *(short8*)(dst + (size_t)i * 8) = r;
}

// ---------------------------------------------- staged GEMM  C = A * W^T
// m97 structure: 128x128 tile, BK=32, global_load_lds width 16, 2 barriers.
// MODE 0: fp32 row-major [M,1024] to outF (O-projection).
// MODE 1: fused QKV (Wm = [3072,1024]). Q/K/V are emitted in MFMA
//   fragment-packed layouts so the attention kernel's loads are perfectly
//   lane-coalesced (base + const + lane*16B):
//   Q,K packed: [tile64 = t>>5 pairs][dt = d>>4][lane = (d&8)*4 + (t&31)][e = d&7]
//   V  packed:  [(t>>6)*2 + (d>>5)][kt = (t>>4)&3][lane = ((t>>3)&1)*32 + (d&31)][e = t&7]
//   Q is additionally pre-scaled by 0.125*log2(e) (softmax scale folded in).
template <int MODE>
__global__ __launch_bounds__(256) void k_gemm_st(const unsigned short* __restrict__ A,
                                                 const unsigned short* __restrict__ Wm,
                                                 float* __restrict__ outF,
                                                 unsigned short* __restrict__ outQ,
                                                 unsigned short* __restrict__ outK,
                                                 unsigned short* __restrict__ outV) {
    __shared__ __align__(16) unsigned short smA[128 * 32];
    __shared__ __align__(16) unsigned short smB[128 * 32];
    const int tid  = threadIdx.x;
    const int lane = tid & 63;
    const int w    = tid >> 6;
    const int lr   = lane & 15;
    const int lg   = lane >> 4;
    const int m0   = blockIdx.y * 128;
    const int n0   = blockIdx.x * 128;
    const int wm   = (w >> 1) * 64;
    const int wn   = (w & 1) * 64;

    const int srow = w * 32 + (lane >> 2);
    const int scol = (lane & 3) * 8;
    const unsigned short* gA0 = A  + (size_t)(m0 + srow) * DMODEL + scol;
    const unsigned short* gB0 = Wm + (size_t)(n0 + srow) * DMODEL + scol;
    unsigned short* lA0 = smA + w * 1024;   // wave-uniform LDS base
    unsigned short* lB0 = smB + w * 1024;

    f32x4 acc[4][4];
#pragma unroll
    for (int i = 0; i < 4; i++)
#pragma unroll
        for (int j = 0; j < 4; j++) acc[i][j] = (f32x4){0.f, 0.f, 0.f, 0.f};

    for (int k0 = 0; k0 < DMODEL; k0 += 32) {
        gld_lds16(gA0 + k0, lA0);
        gld_lds16(gA0 + 16 * DMODEL + k0, lA0 + 16 * 32);
        gld_lds16(gB0 + k0, lB0);
        gld_lds16(gB0 + 16 * DMODEL + k0, lB0 + 16 * 32);
        __syncthreads();
        short8 af[4], bfr[4];
#pragma unroll
        for (int i = 0; i < 4; i++)
            af[i] = *(const short8*)&smA[(wm + 16 * i + lr) * 32 + lg * 8];
#pragma unroll
        for (int j = 0; j < 4; j++)
            bfr[j] = *(const short8*)&smB[(wn + 16 * j + lr) * 32 + lg * 8];
#pragma unroll
        for (int i = 0; i < 4; i++)
#pragma unroll
            for (int j = 0; j < 4; j++)
                acc[i][j] = __builtin_amdgcn_mfma_f32_16x16x32_bf16(af[i], bfr[j], acc[i][j], 0, 0, 0);
        __syncthreads();
    }

    if (MODE == 0) {
#pragma unroll
        for (int i = 0; i < 4; i++)
#pragma unroll
            for (int j = 0; j < 4; j++) {
                int n = n0 + wn + 16 * j + lr;
#pragma unroll
                for (int r = 0; r < 4; r++) {
                    int mm = m0 + wm + 16 * i + lg * 4 + r;
                    outF[(size_t)mm * DMODEL + n] = acc[i][j][r];
                }
            }
    } else {
        const int which = n0 >> 10;          // 0=Q 1=K 2=V
        const int nb = n0 & 1023;
        const float QS = 0.18033688f;        // 0.125 * log2(e), folded into Q
#pragma unroll
        for (int i = 0; i < 4; i++)
#pragma unroll
            for (int j = 0; j < 4; j++) {
                int nloc = nb + wn + 16 * j + lr;
                int h = nloc >> 6, d = nloc & 63;
                int mb = m0 + wm + 16 * i + lg * 4;
                int b = mb >> 11, t = mb & (T_SEQ - 1);
                size_t base = (size_t)(b * NHEADS + h) * T_SEQ * DHEAD;
                if (which == 2) {
                    // V fragment-packed; 4 consecutive t -> 4 consecutive elems
                    int off = ((((t >> 6) * 2 + (d >> 5)) * 4 + ((t >> 4) & 3)) * 64
                               + ((t >> 3) & 1) * 32 + (d & 31)) * 8 + (t & 7);
                    u16x4 pk;
#pragma unroll
                    for (int r = 0; r < 4; r++) pk[r] = f2bf(acc[i][j][r]);
                    *(u16x4*)(outV + base + off) = pk;
                } else {
                    // Q/K fragment-packed; 4 consecutive t -> lane stride 8 elems
                    unsigned short* dst = (which == 0) ? outQ : outK;
                    const float sc = (which == 0) ? QS : 1.0f;
                    int off = (((t >> 5) * 4 + (d >> 4)) * 64 + (d & 8) * 4 + (t & 31)) * 8 + (d & 7);
#pragma unroll
                    for (int r = 0; r < 4; r++)
                        dst[base + off + r * 8] = f2bf(acc[i][j][r] * sc);
                }
            }
    }
}

// ------------------------------------------------------------- attention
// Swapped-QK^T flash attention, 32x32 MFMA.
// Equal-work blocks: 1024 blocks x 4 waves, q-tile pair (63-pr, pr) per block
// (33 KV tiles always), 4-way split-KV per q-tile, rotating-merger LDS merge.
// Q/K/V are in MFMA fragment-packed layouts (see k_gemm_st): every fragment
// load is base + const*512 + lane*8 -> perfectly coalesced 1KB/instruction.
// Q is pre-scaled by 0.125*log2(e).  O: [B,T,1024] bf16.
__global__ __launch_bounds__(256) void k_attn(const unsigned short* __restrict__ Q,
                                              const unsigned short* __restrict__ K,
                                              const unsigned short* __restrict__ Vt,
                                              unsigned short* __restrict__ O) {
    __shared__ float Msm[3][64][35];       // 3 writer slots: 32 O + m + l per lane
    const int tid  = threadIdx.x;
    const int lane = tid & 63;
    const int wv   = tid >> 6;             // 0..3
    const int l31  = lane & 31;
    const int hi   = lane >> 5;
    const bool h0  = (hi == 0);

    const int flat = blockIdx.x;           // 0..1023
    const int xc   = flat & 7;             // XCD chunk for L2 locality
    const int rest = flat >> 3;            // 0..127
    const int hh   = rest >> 5;            // 0..3
    const int pr   = rest & 31;            // pair index 0..31
    const int bh   = xc * 4 + hh;

    const size_t baseQK = (size_t)bh * T_SEQ * DHEAD;
    const unsigned short* Qb = Q  + baseQK;
    const unsigned short* Kb = K  + baseQK;
    const unsigned short* Vb = Vt + baseQK;   // same per-head extent

    for (int phase = 0; phase < 2; ++phase) {
        const int qt = phase ? pr : (63 - pr);   // heavy first
        const int q0 = qt * 32;
        const int ntiles = (qt >> 1) + 1;
        const int qlane = q0 + l31;

        short8 qf[4];
#pragma unroll
        for (int dt = 0; dt < 4; dt++)
            qf[dt] = *(const short8*)(Qb + ((size_t)(qt * 4 + dt) * 64 + lane) * 8);

        f32x16 oa0, oa1;
#pragma unroll
        for (int r = 0; r < 16; r++) { oa0[r] = 0.f; oa1[r] = 0.f; }
        float m = -1e30f, l = 0.f;

        for (int tix = wv; tix < ntiles; tix += 4) {
            short8 vf0[4], vf1[4], kf0[4], kf1[4];
#pragma unroll
            for (int kt = 0; kt < 4; kt++) {
                kf0[kt] = *(const short8*)(Kb + ((size_t)((tix * 2)     * 4 + kt) * 64 + lane) * 8);
                kf1[kt] = *(const short8*)(Kb + ((size_t)((tix * 2 + 1) * 4 + kt) * 64 + lane) * 8);
                vf0[kt] = *(const short8*)(Vb + ((size_t)((tix * 2)     * 4 + kt) * 64 + lane) * 8);
                vf1[kt] = *(const short8*)(Vb + ((size_t)((tix * 2 + 1) * 4 + kt) * 64 + lane) * 8);
            }

            f32x16 s0, s1;
#pragma unroll
            for (int r = 0; r < 16; r++) { s0[r] = 0.f; s1[r] = 0.f; }
#pragma unroll
            for (int dt = 0; dt < 4; dt++)
                s0 = __builtin_amdgcn_mfma_f32_32x32x16_bf16(kf0[dt], qf[dt], s0, 0, 0, 0);
#pragma unroll
            for (int dt = 0; dt < 4; dt++)
                s1 = __builtin_amdgcn_mfma_f32_32x32x16_bf16(kf1[dt], qf[dt], s1, 0, 0, 0);

            if (tix == ntiles - 1) {
                const int thr = qlane - tix * 64;
#pragma unroll
                for (int r = 0; r < 16; r++) {
                    const int koff = (r & 3) + 8 * (r >> 2) + 4 * hi;
                    if (koff > thr)      s0[r] = -1e30f;
                    if (koff + 32 > thr) s1[r] = -1e30f;
                }
            }

            float mt = fmaxf(s0[0], s1[0]);
#pragma unroll
            for (int r = 1; r < 16; r++) mt = fmaxf(mt, fmaxf(s0[r], s1[r]));
            mt = fmaxf(mt, __shfl_xor(mt, 32));

            if (__any(mt > m + 8.0f)) {
                float mn = fmaxf(m, mt);
                float al = exp2f(m - mn);
                m = mn; l *= al;
#pragma unroll
                for (int r = 0; r < 16; r++) { oa0[r] *= al; oa1[r] *= al; }
            }

            f32x16 p0, p1;
            float sa = 0.f, sb = 0.f;
#pragma unroll
            for (int r = 0; r < 16; r++) {
                p0[r] = exp2f(s0[r] - m);
                p1[r] = exp2f(s1[r] - m);
                sa += p0[r]; sb += p1[r];
            }
            float sum = sa + sb;
            sum += __shfl_xor(sum, 32);
            l += sum;

            unsigned int ow0[8], ow1[8], sw0[8], sw1[8];
#pragma unroll
            for (int q_ = 0; q_ < 8; q_++) {
                ow0[q_] = cvtpk(p0[2 * q_], p0[2 * q_ + 1]);
                ow1[q_] = cvtpk(p1[2 * q_], p1[2 * q_ + 1]);
            }
#pragma unroll
            for (int q_ = 0; q_ < 8; q_++) {
                sw0[q_] = __shfl_xor(ow0[q_], 32);
                sw1[q_] = __shfl_xor(ow1[q_], 32);
            }

#define PV_STEP(KT, OW, SW, J) do {                                              \
        u32x4 wvv;                                                               \
        wvv[0] = h0 ? OW[J]     : SW[J + 2];                                     \
        wvv[1] = h0 ? OW[J + 1] : SW[J + 3];                                     \
        wvv[2] = h0 ? SW[J]     : OW[J + 2];                                     \
        wvv[3] = h0 ? SW[J + 1] : OW[J + 3];                                     \
        short8 pf = __builtin_bit_cast(short8, wvv);                             \
        oa0 = __builtin_amdgcn_mfma_f32_32x32x16_bf16(vf0[KT], pf, oa0, 0, 0, 0);\
        oa1 = __builtin_amdgcn_mfma_f32_32x32x16_bf16(vf1[KT], pf, oa1, 0, 0, 0);\
    } while (0)

            PV_STEP(0, ow0, sw0, 0);
            PV_STEP(1, ow0, sw0, 4);
            PV_STEP(2, ow1, sw1, 0);
            PV_STEP(3, ow1, sw1, 4);
#undef PV_STEP
        }

        // ---- 4-way merge: 3 writer waves -> LDS, merger wave combines.
        const int merger = phase;            // rotate merger: phase0->w0, phase1->w1
        if (phase == 1) __syncthreads();     // LDS slots free (phase-0 merger done)
        if (wv != merger) {
            const int slot = wv - (wv > merger ? 1 : 0);   // 0..2
#pragma unroll
            for (int r = 0; r < 16; r++) {
                Msm[slot][lane][r]      = oa0[r];
                Msm[slot][lane][16 + r] = oa1[r];
            }
            Msm[slot][lane][32] = m;
            Msm[slot][lane][33] = l;
        }
        __syncthreads();
        if (wv == merger) {
            float ms[3], ls[3];
            float mtot = m;
#pragma unroll
            for (int s = 0; s < 3; s++) {
                ms[s] = Msm[s][lane][32];
                ls[s] = Msm[s][lane][33];
                mtot = fmaxf(mtot, ms[s]);
            }
            const float fo = exp2f(m - mtot);
            float fs[3];
            float lt = l * fo;
#pragma unroll
            for (int s = 0; s < 3; s++) {
                fs[s] = exp2f(ms[s] - mtot);
                lt += ls[s] * fs[s];
            }
            const float inv = 1.0f / lt;
            const int b = bh >> 4, h = bh & 15;
            unsigned short* orow = O + ((size_t)(b * T_SEQ + qlane)) * DMODEL + h * DHEAD;
#pragma unroll
            for (int rg = 0; rg < 4; rg++) {
                u16x4 pk0, pk1;
#pragma unroll
                for (int jj = 0; jj < 4; jj++) {
                    const int idx = 4 * rg + jj;
                    float v0 = oa0[idx] * fo;
                    float v1 = oa1[idx] * fo;
#pragma unroll
                    for (int s = 0; s < 3; s++) {
                        v0 += Msm[s][lane][idx]      * fs[s];
                        v1 += Msm[s][lane][16 + idx] * fs[s];
                    }
                    pk0[jj] = f2bf(v0 * inv);
                    pk1[jj] = f2bf(v1 * inv);
                }
                *(u16x4*)(orow + 4 * hi + 8 * rg) = pk0;
                *(u16x4*)(orow + 32 + 4 * hi + 8 * rg) = pk1;
            }
        }
    }
}

// ---------------------------------------------------------------- launch
extern "C" void kernel_launch(void* const* d_in, const int* in_sizes, int n_in,
                              void* d_out, int out_size, void* d_ws, size_t ws_size,
                              hipStream_t stream) {
    const float* x  = (const float*)d_in[0];
    // d_in[1] = causal mask (tril) -- structure is hardcoded
    const float* Wq = (const float*)d_in[2];
    const float* Wk = (const float*)d_in[3];
    const float* Wv = (const float*)d_in[4];
    const float* Wo = (const float*)d_in[5];

    unsigned short* wsu = (unsigned short*)d_ws;
    const size_t WELE = (size_t)DMODEL * DMODEL;         // 1,048,576
    unsigned short* Wo_bf = wsu + 3 * WELE;
    unsigned short* x_bf  = wsu + 4 * WELE;              // [4096,1024]; reused as attn out
    unsigned short* Qp    = wsu + 8 * WELE;              // fragment-packed Q
    unsigned short* Kp    = wsu + 12 * WELE;             // fragment-packed K
    unsigned short* Vp    = wsu + 16 * WELE;             // fragment-packed V
    if (ws_size < 20 * WELE * sizeof(unsigned short)) return;  // need 40 MB

    const int n8x = (MROWS * DMODEL) / 8;   // 524288
    const int n8w = (DMODEL * DMODEL) / 8;  // 131072
    k_convert<<<dim3((n8x + 255) / 256), 256, 0, stream>>>(x, x_bf, n8x);
    k_convert4<<<dim3((n8w + 255) / 256, 4), 256, 0, stream>>>(Wq, Wk, Wv, Wo, wsu, n8w);

    // fused QKV projection: N = 3072
    k_gemm_st<1><<<dim3(3 * DMODEL / 128, MROWS / 128), 256, 0, stream>>>(
        x_bf, wsu, nullptr, Qp, Kp, Vp);

    k_attn<<<dim3(1024), 256, 0, stream>>>(Qp, Kp, Vp, x_bf);

    k_gemm_st<0><<<dim3(DMODEL / 128, MROWS / 128), 256, 0, stream>>>(
        x_bf, Wo_bf, (float*)d_out, nullptr, nullptr, nullptr);
}